// Round 1
// baseline (67.501 us; speedup 1.0000x reference)
//
#include <hip/hip_runtime.h>

// Izhikevich 'RS' parameters (must match reference bit-for-bit in f32)
#define N_LHB_C  2000000
#define N_RMHB_C 500000
#define N_LMHB_C 500000
#define STEPS_C  20

// One Euler step, exact numpy-f32 evaluation order, contraction-proof.
__device__ __forceinline__ void izh_step(float& v, float& u, float& r, float& acc,
                                         float nz, float i_base) {
    float I = __fadd_rn(i_base, __fmul_rn(nz, 0.5f));
    float t0 = __fmul_rn(__fmul_rn(0.04f, v), v);   // 0.04*v*v
    t0 = __fadd_rn(t0, __fmul_rn(5.0f, v));          // + 5*v
    t0 = __fadd_rn(t0, 140.0f);                      // + 140
    t0 = __fsub_rn(t0, u);                           // - u
    t0 = __fadd_rn(t0, I);                           // + I
    float v2 = __fadd_rn(v, t0);                     // v + (...)
    float inner = __fsub_rn(__fmul_rn(0.2f, v2), u); // B*v2 - u
    float u2 = __fadd_rn(u, __fmul_rn(0.02f, inner));// u + A*(...)
    bool fired = (v2 >= 30.0f);
    v = fired ? -65.0f : v2;
    u = fired ? __fadd_rn(u2, 8.0f) : u2;            // u2 + spk*D
    r = __fadd_rn(__fmul_rn(r, 0.95f), fired ? 0.05f : 0.0f);
    acc += fired ? 1.0f : 0.0f;
}

// mode: 0 = LHB (spikes_out != nullptr), 1 = RMHB, 2 = LMHB
__global__ __launch_bounds__(256) void izh_pop_kernel(
    const float* __restrict__ v_in, const float* __restrict__ u_in,
    const float* __restrict__ rate_in, const float* __restrict__ noise,
    int n,
    const float* __restrict__ reward_p, const float* __restrict__ expref_p,
    const float* __restrict__ aversion_p, int mode,
    float* __restrict__ spikes_out, float* __restrict__ rate_out,
    float* __restrict__ partials)
{
    const int tid = threadIdx.x;
    const int gid = blockIdx.x * 256 + tid;
    const int base = gid * 4;

    float i_base;
    if (mode == 0) {
        float rpe = __fsub_rn(reward_p[0], expref_p[0]);
        float dis = fmaxf(0.0f, -rpe);
        i_base = __fadd_rn(__fmul_rn(dis, 20.0f), -1.0f);
    } else if (mode == 1) {
        i_base = __fadd_rn(__fmul_rn(aversion_p[0], 18.0f), -0.5f);
    } else {
        i_base = __fadd_rn(__fmul_rn(aversion_p[0], 10.0f), -1.5f);
    }

    float rsum = 0.0f;

    if (base + 3 < n) {
        float4 v4 = *reinterpret_cast<const float4*>(v_in + base);
        float4 u4 = *reinterpret_cast<const float4*>(u_in + base);
        float4 r4 = *reinterpret_cast<const float4*>(rate_in + base);
        float v[4] = {v4.x, v4.y, v4.z, v4.w};
        float u[4] = {u4.x, u4.y, u4.z, u4.w};
        float r[4] = {r4.x, r4.y, r4.z, r4.w};
        float acc[4] = {0.0f, 0.0f, 0.0f, 0.0f};

        for (int t = 0; t < STEPS_C; ++t) {
            float4 nz = *reinterpret_cast<const float4*>(noise + (size_t)t * n + base);
            izh_step(v[0], u[0], r[0], acc[0], nz.x, i_base);
            izh_step(v[1], u[1], r[1], acc[1], nz.y, i_base);
            izh_step(v[2], u[2], r[2], acc[2], nz.z, i_base);
            izh_step(v[3], u[3], r[3], acc[3], nz.w, i_base);
        }

        *reinterpret_cast<float4*>(rate_out + base) = make_float4(r[0], r[1], r[2], r[3]);
        if (spikes_out) {
            *reinterpret_cast<float4*>(spikes_out + base) =
                make_float4(acc[0], acc[1], acc[2], acc[3]);
        }
        rsum = __fadd_rn(__fadd_rn(__fadd_rn(r[0], r[1]), r[2]), r[3]);
    } else if (base < n) {
        // scalar tail (not hit for the given sizes, kept for safety)
        for (int k = base; k < n; ++k) {
            float v = v_in[k], u = u_in[k], r = rate_in[k], acc = 0.0f;
            for (int t = 0; t < STEPS_C; ++t)
                izh_step(v, u, r, acc, noise[(size_t)t * n + k], i_base);
            rate_out[k] = r;
            if (spikes_out) spikes_out[k] = acc;
            rsum = __fadd_rn(rsum, r);
        }
    }

    // deterministic block reduction of rate sum
    __shared__ float sdata[256];
    sdata[tid] = rsum;
    __syncthreads();
    for (int s = 128; s > 0; s >>= 1) {
        if (tid < s) sdata[tid] = __fadd_rn(sdata[tid], sdata[tid + s]);
        __syncthreads();
    }
    if (tid == 0) partials[blockIdx.x] = sdata[0];
}

__global__ __launch_bounds__(256) void finalize_kernel(
    const float* __restrict__ pl, int nl,
    const float* __restrict__ pr, int nr,
    const float* __restrict__ pm, int nm,
    const float* __restrict__ frustration,
    const float* __restrict__ reward_p, const float* __restrict__ expref_p,
    const float* __restrict__ aversion_p, const float* __restrict__ da_p,
    const int* __restrict__ goal_p,
    float* __restrict__ out_tail /* 11 scalars + 4 goal_bias */)
{
    __shared__ float s0[256], s1[256], s2[256];
    const int tid = threadIdx.x;
    float a = 0.0f, b = 0.0f, c = 0.0f;
    for (int i = tid; i < nl; i += 256) a = __fadd_rn(a, pl[i]);
    for (int i = tid; i < nr; i += 256) b = __fadd_rn(b, pr[i]);
    for (int i = tid; i < nm; i += 256) c = __fadd_rn(c, pm[i]);
    s0[tid] = a; s1[tid] = b; s2[tid] = c;
    __syncthreads();
    for (int s = 128; s > 0; s >>= 1) {
        if (tid < s) {
            s0[tid] = __fadd_rn(s0[tid], s0[tid + s]);
            s1[tid] = __fadd_rn(s1[tid], s1[tid + s]);
            s2[tid] = __fadd_rn(s2[tid], s2[tid + s]);
        }
        __syncthreads();
    }
    if (tid != 0) return;

    const float lhb_mean  = s0[0] / (float)N_LHB_C;
    const float rmhb_mean = s1[0] / (float)N_RMHB_C;
    const float lmhb_mean = s2[0] / (float)N_LMHB_C;
    const float mhb_mean  = __fadd_rn(__fmul_rn(0.67f, rmhb_mean),
                                      __fmul_rn(0.33f, lmhb_mean));

    const float reward = reward_p[0], expref = expref_p[0];
    const float aversion = aversion_p[0]; (void)aversion;
    const float DA = da_p[0];
    const int cg = goal_p[0];

    const float rpe = __fsub_rn(reward, expref);
    const float disappoint = fmaxf(0.0f, -rpe);

    const float da_supp  = fminf(0.5f, __fmul_rn(lhb_mean, 5.0f));
    const float ht5_supp = fminf(0.3f, __fmul_rn(lhb_mean, 3.0f));
    const float ach_ipn  = fminf(1.0f, __fmul_rn(rmhb_mean, 4.0f));
    const float explore  = fminf(1.0f, __fadd_rn(__fmul_rn(disappoint, 2.0f),
                                                 __fmul_rn(lhb_mean, 3.0f)));

    float fr[4];
    for (int i = 0; i < 4; ++i) fr[i] = __fmul_rn(frustration[i], 0.998f);
    // fr.at[cg].add(where(rpe < -0.05, GAIN*|rpe|, 0))
    fr[cg] = __fadd_rn(fr[cg], (rpe < -0.05f) ? __fmul_rn(0.05f, fabsf(rpe)) : 0.0f);
    // fr.at[cg].multiply(where(rpe > 0.1, 0.8, 1.0))
    fr[cg] = __fmul_rn(fr[cg], (rpe > 0.1f) ? 0.8f : 1.0f);
    for (int i = 0; i < 4; ++i) fr[i] = fminf(fmaxf(fr[i], 0.0f), 1.0f);
    float helplessness = fr[0];
    for (int i = 1; i < 4; ++i) helplessness = fmaxf(helplessness, fr[i]);
    const float sw = (fr[cg] > 0.4f) ? 1.0f : 0.0f;
    fr[cg] = __fmul_rn(fr[cg], (sw > 0.0f) ? 0.3f : 1.0f);

    const float dopa_mod = fmaxf(0.5f, __fmul_rn(2.0f, __fsub_rn(1.0f, DA)));

    out_tail[0]  = disappoint;
    out_tail[1]  = da_supp;
    out_tail[2]  = ht5_supp;
    out_tail[3]  = lhb_mean;
    out_tail[4]  = mhb_mean;
    out_tail[5]  = rmhb_mean;
    out_tail[6]  = lmhb_mean;
    out_tail[7]  = ach_ipn;
    out_tail[8]  = explore;
    out_tail[9]  = sw;
    out_tail[10] = helplessness;
    for (int i = 0; i < 4; ++i)
        out_tail[11 + i] = __fmul_rn(__fmul_rn(fr[i], 0.5f), dopa_mod);
}

extern "C" void kernel_launch(void* const* d_in, const int* in_sizes, int n_in,
                              void* d_out, int out_size, void* d_ws, size_t ws_size,
                              hipStream_t stream) {
    const float* v_lhb    = (const float*)d_in[0];
    const float* u_lhb    = (const float*)d_in[1];
    const float* rate_lhb = (const float*)d_in[2];
    const float* v_rmhb   = (const float*)d_in[3];
    const float* u_rmhb   = (const float*)d_in[4];
    const float* rate_rmhb= (const float*)d_in[5];
    const float* v_lmhb   = (const float*)d_in[6];
    const float* u_lmhb   = (const float*)d_in[7];
    const float* rate_lmhb= (const float*)d_in[8];
    const float* noise_lhb  = (const float*)d_in[9];
    const float* noise_rmhb = (const float*)d_in[10];
    const float* noise_lmhb = (const float*)d_in[11];
    const float* frustration = (const float*)d_in[12];
    const float* reward_p    = (const float*)d_in[13];
    const float* expref_p    = (const float*)d_in[14];
    const float* aversion_p  = (const float*)d_in[15];
    const float* da_p        = (const float*)d_in[16];
    const int*   goal_p      = (const int*)d_in[17];

    const int n_lhb  = in_sizes[0];
    const int n_rmhb = in_sizes[3];
    const int n_lmhb = in_sizes[6];

    float* out = (float*)d_out;
    float* out_lhb_spikes = out;
    float* out_lhb_rate   = out + n_lhb;
    float* out_rmhb_rate  = out + 2 * (size_t)n_lhb;
    float* out_lmhb_rate  = out + 2 * (size_t)n_lhb + n_rmhb;
    float* out_tail       = out + 2 * (size_t)n_lhb + n_rmhb + n_lmhb;

    const int blk_lhb  = (n_lhb  / 4 + 255) / 256 + ((n_lhb  % 4) ? 1 : 0);
    const int blk_rmhb = (n_rmhb / 4 + 255) / 256 + ((n_rmhb % 4) ? 1 : 0);
    const int blk_lmhb = (n_lmhb / 4 + 255) / 256 + ((n_lmhb % 4) ? 1 : 0);

    float* wsf = (float*)d_ws;
    float* pl = wsf;
    float* pr = wsf + blk_lhb;
    float* pm = wsf + blk_lhb + blk_rmhb;

    izh_pop_kernel<<<blk_lhb, 256, 0, stream>>>(
        v_lhb, u_lhb, rate_lhb, noise_lhb, n_lhb,
        reward_p, expref_p, aversion_p, 0,
        out_lhb_spikes, out_lhb_rate, pl);

    izh_pop_kernel<<<blk_rmhb, 256, 0, stream>>>(
        v_rmhb, u_rmhb, rate_rmhb, noise_rmhb, n_rmhb,
        reward_p, expref_p, aversion_p, 1,
        nullptr, out_rmhb_rate, pr);

    izh_pop_kernel<<<blk_lmhb, 256, 0, stream>>>(
        v_lmhb, u_lmhb, rate_lmhb, noise_lmhb, n_lmhb,
        reward_p, expref_p, aversion_p, 2,
        nullptr, out_lmhb_rate, pm);

    finalize_kernel<<<1, 256, 0, stream>>>(
        pl, blk_lhb, pr, blk_rmhb, pm, blk_lmhb,
        frustration, reward_p, expref_p, aversion_p, da_p, goal_p,
        out_tail);
}